// Round 8
// baseline (288.968 us; speedup 1.0000x reference)
//
#include <hip/hip_runtime.h>
#include <hip/hip_bf16.h>

#define NB    4
#define HH    96
#define WW    96
#define PIX   9216
#define C0    324
#define MM    48
#define NROI  192
#define NPAIR 9216
#define KHEAD 6468
#define KRF   6272
#define SPLITS 28
#define CPS    7     // 28*7*32 = 6272

// conv2/3 weight stage: 9 taps x 4 octiles x 64 lanes x 8 = 18432 elems per (ocb,icb)
#define CWSTG 18432

typedef unsigned short u16;
typedef __attribute__((ext_vector_type(8))) short bf16x8;
typedef __attribute__((ext_vector_type(4))) float f32x4;
typedef __attribute__((ext_vector_type(16))) float f32x16;
typedef __attribute__((ext_vector_type(4))) unsigned short u16x4;
typedef __attribute__((ext_vector_type(8))) unsigned short u16x8;
typedef __attribute__((ext_vector_type(4))) int i32x4;

__device__ __forceinline__ u16 f2bf(float f) {
    __hip_bfloat16 h = __float2bfloat16(f);
    union { __hip_bfloat16 h; u16 u; } c; c.h = h; return c.u;
}
__device__ __forceinline__ float b2f(u16 u) {
    union { unsigned int i; float f; } c; c.i = ((unsigned int)u) << 16; return c.f;
}

// ---------------------------------------------------------------------------
// Merged prep + halo-zero (unchanged from R6 — verified layouts).
__global__ __launch_bounds__(256) void prep_v2(
    const float* __restrict__ c1w, const float* __restrict__ c2w,
    const float* __restrict__ c3w, const float* __restrict__ hw,
    const float* __restrict__ f6w, const float* __restrict__ f7w,
    u16* __restrict__ wt1f, u16* __restrict__ wt2f, u16* __restrict__ wt3f,
    u16* __restrict__ wtHt, u16* __restrict__ w6c, u16* __restrict__ w7c,
    float* __restrict__ wsum4, u16* __restrict__ a1, u16* __restrict__ a2)
{
    __shared__ u16 L[18432];
    const int blk = blockIdx.x, tid = threadIdx.x;

    if (blk < 8) {
        const int ot = blk;
        const float* src = c1w + (size_t)ot * 32 * C0;
        for (int it = 0; it < 11; ++it) {
            int i = tid + it * 256;
            if (i < 2592) {
                float4 v = *(const float4*)(src + i * 4);
                int n = i / 81, k4 = (i % 81) * 4;
                L[n * 324 + k4 + 0] = f2bf(v.x);
                L[n * 324 + k4 + 1] = f2bf(v.y);
                L[n * 324 + k4 + 2] = f2bf(v.z);
                L[n * 324 + k4 + 3] = f2bf(v.w);
            }
        }
        __syncthreads();
        for (int it = 0; it < 6; ++it) {
            int v = tid + it * 256;
            if (v >= 1408) break;
            int ks = v >> 6, lane = v & 63;
            int n = lane & 31, half = lane >> 5;
            u16x8 pk;
            #pragma unroll
            for (int j = 0; j < 8; ++j) {
                int k = ks * 16 + half * 8 + j;
                pk[j] = (k < C0) ? L[n * 324 + k] : (u16)0;
            }
            *(u16x8*)&wt1f[((ks * 8 + ot) * 64 + lane) * 8] = pk;
        }
    } else if (blk < 56) {
        const bool is2 = blk < 40;
        const int b8 = is2 ? (blk - 8) : (blk - 40);
        const int oc8 = b8 * 8;
        const int ocb = oc8 >> 7;
        const int ot = (oc8 >> 5) & 3;
        const int nb = oc8 & 31;
        const float* src = (is2 ? c2w : c3w) + (size_t)oc8 * 2304;
        u16* dst = is2 ? wt2f : wt3f;
        for (int it = 0; it < 18; ++it) {
            int i = tid + it * 256;
            float4 v = *(const float4*)(src + i * 4);
            int n = i / 576, t4 = (i % 576) * 4;
            L[n * 2304 + t4 + 0] = f2bf(v.x);
            L[n * 2304 + t4 + 1] = f2bf(v.y);
            L[n * 2304 + t4 + 2] = f2bf(v.z);
            L[n * 2304 + t4 + 3] = f2bf(v.w);
        }
        __syncthreads();
        for (int it = 0; it < 9; ++it) {
            int v = tid + it * 256;
            int o8 = v & 7; int rest = v >> 3;
            int half = rest & 1; rest >>= 1;
            int tap = rest % 9; int icb = rest / 9;
            int lane = half * 32 + nb + o8;
            u16x8 pk;
            #pragma unroll
            for (int j = 0; j < 8; ++j) {
                int ic = icb * 16 + half * 8 + j;
                pk[j] = L[o8 * 2304 + ic * 9 + tap];
            }
            size_t dest = ((((size_t)(ocb * 16 + icb) * 9 + tap) * 4 + ot) * 64 + lane) * 8;
            *(u16x8*)&dst[dest] = pk;
        }
    } else if (blk < 312) {
        const int oc = blk - 56;
        const float* src = hw + (size_t)oc * KHEAD;
        for (int it = 0; it < 7; ++it) {
            int i = tid + it * 256;
            if (i < 1617) {
                float4 v = *(const float4*)(src + i * 4);
                L[i * 4 + 0] = f2bf(v.x);
                L[i * 4 + 1] = f2bf(v.y);
                L[i * 4 + 2] = f2bf(v.z);
                L[i * 4 + 3] = f2bf(v.w);
            }
        }
        if (tid < 4) {
            const float* p = src + (128 + tid) * 49;
            float s = 0.f;
            #pragma unroll
            for (int t = 0; t < 49; ++t) s += p[t];
            wsum4[oc * 4 + tid] = s;
        }
        __syncthreads();
        for (int it = 0; it < 4; ++it) {
            int v = tid + it * 256;
            if (v >= 784) break;
            u16x8 pk;
            #pragma unroll
            for (int j = 0; j < 8; ++j) {
                int r = v * 8 + j;
                int s = r >> 7, c = r & 127;
                pk[j] = L[c * 49 + s];
            }
            *(u16x8*)&wtHt[(size_t)oc * KRF + v * 8] = pk;
        }
    } else if (blk < 344) {
        const bool is6 = blk < 328;
        const int b = is6 ? (blk - 312) : (blk - 328);
        const float* src = (is6 ? f6w : f7w) + (size_t)(b * 256 + tid) * 16;
        u16* dst = (is6 ? w6c : w7c) + (size_t)(b * 256 + tid) * 16;
        u16x8 pk0, pk1;
        #pragma unroll
        for (int h = 0; h < 2; ++h) {
            float4 v0 = *(const float4*)(src + h * 8);
            float4 v1 = *(const float4*)(src + h * 8 + 4);
            u16x8 pk;
            pk[0] = f2bf(v0.x); pk[1] = f2bf(v0.y); pk[2] = f2bf(v0.z); pk[3] = f2bf(v0.w);
            pk[4] = f2bf(v1.x); pk[5] = f2bf(v1.y); pk[6] = f2bf(v1.z); pk[7] = f2bf(v1.w);
            if (h == 0) pk0 = pk; else pk1 = pk;
        }
        *(u16x8*)(dst + 0) = pk0;
        *(u16x8*)(dst + 8) = pk1;
    } else {
        int idx = (blk - 344) * 256 + tid;
        int c8 = idx & 31;
        int t = idx >> 5;
        int h = t % 388, img = t / 388;
        u16* base = (img & 4) ? a2 : a1;
        int b = img & 3;
        int y, x;
        if (h < 98)       { y = 0;  x = h; }
        else if (h < 196) { y = 97; x = h - 98; }
        else { int r = (h - 196) >> 1; x = ((h - 196) & 1) * 97; y = 1 + r; }
        long long off = (((long long)(b * 98 + y)) * 98 + x) * 256 + c8 * 8;
        i32x4 z = {0, 0, 0, 0};
        *(i32x4*)(base + off) = z;
    }
}

// ---------------------------------------------------------------------------
// conv1 (1x1, K=324->352) fused fp32 transpose + 32x32x16 MFMA.
// v3: transpose thread mapping kr = tid&31 -> LDS write conflicts 16-way -> 4-way.
__global__ __launch_bounds__(256) void conv1_v3(
    const float* __restrict__ corr, const u16* __restrict__ wf,
    const float* __restrict__ bias, u16* __restrict__ outp)
{
    __shared__ __align__(16) u16 Ws1[8192];
    __shared__ __align__(16) u16 Bs[64 * 40];
    const int tid = threadIdx.x;
    const int b = blockIdx.y;
    const int p0 = blockIdx.x * 64;
    const int lane = tid & 63, wid = tid >> 6;
    const int n = lane & 31, half = lane >> 5;
    const int wocw = wid & 1, wpx = wid >> 1;
    const int kr = tid & 31, pg = tid >> 5;    // k-row 0..31, px-group 0..7 (8 px)

    f32x16 acc[4];
    #pragma unroll
    for (int i = 0; i < 4; ++i)
        #pragma unroll
        for (int e = 0; e < 16; ++e) acc[i][e] = 0.f;

    float4 s0 = {0,0,0,0}, s1 = {0,0,0,0};
    {
        const float* src = &corr[((long long)(b * C0 + kr)) * PIX + p0 + pg * 8];
        s0 = *(const float4*)src; s1 = *(const float4*)(src + 4);
    }
    bf16x8 wr[4];
    #pragma unroll
    for (int i = 0; i < 4; ++i) wr[i] = *(const bf16x8*)(wf + (i * 256 + tid) * 8);

    for (int kc = 0; kc < 11; ++kc) {
        __syncthreads();
        Bs[(pg * 8 + 0) * 40 + kr] = f2bf(s0.x);
        Bs[(pg * 8 + 1) * 40 + kr] = f2bf(s0.y);
        Bs[(pg * 8 + 2) * 40 + kr] = f2bf(s0.z);
        Bs[(pg * 8 + 3) * 40 + kr] = f2bf(s0.w);
        Bs[(pg * 8 + 4) * 40 + kr] = f2bf(s1.x);
        Bs[(pg * 8 + 5) * 40 + kr] = f2bf(s1.y);
        Bs[(pg * 8 + 6) * 40 + kr] = f2bf(s1.z);
        Bs[(pg * 8 + 7) * 40 + kr] = f2bf(s1.w);
        #pragma unroll
        for (int i = 0; i < 4; ++i) *(bf16x8*)&Ws1[(i * 256 + tid) * 8] = wr[i];
        __syncthreads();
        if (kc < 10) {
            int k = (kc + 1) * 32 + kr;
            if (k < C0) {
                const float* src = &corr[((long long)(b * C0 + k)) * PIX + p0 + pg * 8];
                s0 = *(const float4*)src; s1 = *(const float4*)(src + 4);
            } else { s0 = (float4){0,0,0,0}; s1 = (float4){0,0,0,0}; }
            const u16* wn = wf + (kc + 1) * 8192;
            #pragma unroll
            for (int i = 0; i < 4; ++i) wr[i] = *(const bf16x8*)(wn + (i * 256 + tid) * 8);
        }
        #pragma unroll
        for (int ks = 0; ks < 2; ++ks) {
            bf16x8 bb = *(const bf16x8*)&Bs[(wpx * 32 + n) * 40 + ks * 16 + half * 8];
            #pragma unroll
            for (int ot = 0; ot < 4; ++ot) {
                bf16x8 a = *(const bf16x8*)&Ws1[((ks * 8 + wocw * 4 + ot) * 64 + lane) * 8];
                acc[ot] = __builtin_amdgcn_mfma_f32_32x32x16_bf16(a, bb, acc[ot], 0, 0, 0);
            }
        }
    }
    const int px = p0 + wpx * 32 + n;
    const int y = px / 96, x = px % 96;
    const long long obase = (((long long)(b * 98 + y + 1)) * 98 + x + 1) * 256;
    #pragma unroll
    for (int ot = 0; ot < 4; ++ot) {
        int ocb = wocw * 128 + ot * 32;
        f32x16 d = acc[ot];
        #pragma unroll
        for (int r2 = 0; r2 < 4; ++r2) {
            int oc4 = ocb + r2 * 8 + half * 4;
            f32x4 bv = *(const f32x4*)(bias + oc4);
            u16x4 pk;
            #pragma unroll
            for (int g = 0; g < 4; ++g) pk[g] = f2bf(fmaxf(d[r2 * 4 + g] + bv[g], 0.f));
            *(u16x4*)(outp + obase + oc4) = pk;
        }
    }
}

// ---------------------------------------------------------------------------
// conv3x3 32x32x16 MFMA, v4: 256-px tiles (8 rows x 32 cols).
// Wave = 64 oc x (4 rows x 32 cols): per stage 18 A + 18 B reads feed 72 MFMAs
// (0.5 reads/MFMA). Halo 10x34. Grid: (36, COUT/128, 4) -> 288/144 blocks,
// all-resident, no queue tail.
template<int COUT, bool PADOUT>
__global__ __launch_bounds__(256, 2) void conv3x3_v4(
    const u16* __restrict__ inp, const u16* __restrict__ wf,
    const float* __restrict__ bias, u16* __restrict__ outp)
{
    __shared__ __align__(16) u16 Ws[CWSTG];      // [tap9][ot4][lane64][8]
    __shared__ __align__(16) u16 Hs[340 * 24];   // [row10][col34][ic16 pad24]
    const int tid = threadIdx.x;
    const int b = blockIdx.z;
    const int x0 = (blockIdx.x % 3) * 32, y0 = (blockIdx.x / 3) * 8;
    const int lane = tid & 63, wid = tid >> 6;
    const int n = lane & 31, half = lane >> 5;
    const int woc = wid & 1, wpx = wid >> 1;

    const u16* wsrc = wf + (size_t)blockIdx.y * 16 * CWSTG;
    const bool hst = tid < 170;
    const int h0 = tid, h1 = tid + 170;          // h1 <= 339
    const int r0 = h0 / 34, c0 = h0 % 34;
    const int r1 = h1 / 34, c1 = h1 % 34;
    const u16* hsrc0 = inp + (((size_t)(b * 98 + y0 + r0)) * 98 + x0 + c0) * 256;
    const u16* hsrc1 = inp + (((size_t)(b * 98 + y0 + r1)) * 98 + x0 + c1) * 256;

    f32x16 acc[2][4];
    #pragma unroll
    for (int i = 0; i < 2; ++i)
        #pragma unroll
        for (int r = 0; r < 4; ++r)
            #pragma unroll
            for (int e = 0; e < 16; ++e) acc[i][r][e] = 0.f;

    bf16x8 wreg[9];
    bf16x8 ha0, ha1, hb0, hb1;
    #pragma unroll
    for (int it = 0; it < 9; ++it)
        wreg[it] = *(const bf16x8*)(wsrc + (it * 256 + tid) * 8);
    if (hst) {
        ha0 = *(const bf16x8*)hsrc0; ha1 = *(const bf16x8*)(hsrc0 + 8);
        hb0 = *(const bf16x8*)hsrc1; hb1 = *(const bf16x8*)(hsrc1 + 8);
    }

    for (int icb = 0; icb < 16; ++icb) {
        __syncthreads();
        #pragma unroll
        for (int it = 0; it < 9; ++it)
            *(bf16x8*)&Ws[(it * 256 + tid) * 8] = wreg[it];
        if (hst) {
            *(bf16x8*)&Hs[h0 * 24]     = ha0;
            *(bf16x8*)&Hs[h0 * 24 + 8] = ha1;
            *(bf16x8*)&Hs[h1 * 24]     = hb0;
            *(bf16x8*)&Hs[h1 * 24 + 8] = hb1;
        }
        __syncthreads();
        if (icb < 15) {
            const u16* wn = wsrc + (size_t)(icb + 1) * CWSTG;
            #pragma unroll
            for (int it = 0; it < 9; ++it)
                wreg[it] = *(const bf16x8*)(wn + (it * 256 + tid) * 8);
            if (hst) {
                const u16* p0n = hsrc0 + (icb + 1) * 16;
                const u16* p1n = hsrc1 + (icb + 1) * 16;
                ha0 = *(const bf16x8*)p0n; ha1 = *(const bf16x8*)(p0n + 8);
                hb0 = *(const bf16x8*)p1n; hb1 = *(const bf16x8*)(p1n + 8);
            }
        }
        #pragma unroll
        for (int dx = 0; dx < 3; ++dx) {
            bf16x8 B[6];
            #pragma unroll
            for (int j = 0; j < 6; ++j)
                B[j] = *(const bf16x8*)&Hs[((wpx * 4 + j) * 34 + n + dx) * 24 + half * 8];
            #pragma unroll
            for (int dyi = 0; dyi < 3; ++dyi) {
                const int tap = dyi * 3 + dx;
                bf16x8 A0 = *(const bf16x8*)&Ws[((tap * 4 + woc * 2 + 0) * 64 + lane) * 8];
                bf16x8 A1 = *(const bf16x8*)&Ws[((tap * 4 + woc * 2 + 1) * 64 + lane) * 8];
                #pragma unroll
                for (int r = 0; r < 4; ++r) {
                    acc[0][r] = __builtin_amdgcn_mfma_f32_32x32x16_bf16(A0, B[r + dyi], acc[0][r], 0, 0, 0);
                    acc[1][r] = __builtin_amdgcn_mfma_f32_32x32x16_bf16(A1, B[r + dyi], acc[1][r], 0, 0, 0);
                }
            }
        }
    }
    #pragma unroll
    for (int ot = 0; ot < 2; ++ot) {
        int ocb = blockIdx.y * 128 + woc * 64 + ot * 32;
        #pragma unroll
        for (int r = 0; r < 4; ++r) {
            int y = y0 + wpx * 4 + r;
            int x = x0 + n;
            f32x16 d = acc[ot][r];
            long long obase;
            if (PADOUT) obase = (((long long)(b * 98 + y + 1)) * 98 + x + 1) * COUT;
            else        obase = (((long long)(b * 96 + y)) * 96 + x) * COUT;
            #pragma unroll
            for (int r2 = 0; r2 < 4; ++r2) {
                int oc4 = ocb + r2 * 8 + half * 4;
                f32x4 bv = *(const f32x4*)(bias + oc4);
                u16x4 pk;
                #pragma unroll
                for (int g = 0; g < 4; ++g) pk[g] = f2bf(fmaxf(d[r2 * 4 + g] + bv[g], 0.f));
                *(u16x4*)(outp + obase + oc4) = pk;
            }
        }
    }
}

// ---------------------------------------------------------------------------
// ROI align: rel [4][96][96][128] bf16 -> rf [192][6272] bf16 (k' = s*128+c)
__global__ __launch_bounds__(256) void roi_align_cl(
    const u16* __restrict__ rel, const float* __restrict__ det1,
    u16* __restrict__ rf)
{
    const int roi = blockIdx.x, tid = threadIdx.x;
    const int c = tid & 127, sb = tid >> 7;
    const int b = roi / MM, m = roi % MM;
    const float* d = det1 + (long long)(b * MM + m) * 10;
    float cx = d[2], cy = d[3], w = d[4], h = d[5];
    float x1f = cx - w * 0.5f, y1f = cy - h * 0.5f;
    float x1 = x1f * 0.125f, y1 = y1f * 0.125f;
    float x2 = (x1f + w) * 0.125f, y2 = (y1f + h) * 0.125f;
    float bh = (y2 - y1) * (1.f / 7.f), bw = (x2 - x1) * (1.f / 7.f);
    const u16* fb = rel + (long long)b * PIX * 128 + c;
    for (int s = sb; s < 49; s += 2) {
        int i = s / 7, j = s % 7;
        float sum = 0.f;
        #pragma unroll
        for (int di = 0; di < 2; ++di) {
            float y = y1 + ((float)(2 * i + di) + 0.5f) * 0.5f * bh;
            y = fminf(fmaxf(y, 0.f), 95.f);
            int yy0 = (int)floorf(y);
            int yy1 = min(yy0 + 1, 95);
            float wy = y - (float)yy0;
            #pragma unroll
            for (int dj = 0; dj < 2; ++dj) {
                float x = x1 + ((float)(2 * j + dj) + 0.5f) * 0.5f * bw;
                x = fminf(fmaxf(x, 0.f), 95.f);
                int xx0 = (int)floorf(x);
                int xx1 = min(xx0 + 1, 95);
                float wx = x - (float)xx0;
                float f00 = b2f(fb[((long long)yy0 * 96 + xx0) * 128]);
                float f01 = b2f(fb[((long long)yy0 * 96 + xx1) * 128]);
                float f10 = b2f(fb[((long long)yy1 * 96 + xx0) * 128]);
                float f11 = b2f(fb[((long long)yy1 * 96 + xx1) * 128]);
                sum += f00 * (1.f - wy) * (1.f - wx) + f01 * (1.f - wy) * wx
                     + f10 * wy * (1.f - wx) + f11 * wy * wx;
            }
        }
        rf[(long long)roi * KRF + s * 128 + c] = f2bf(sum * 0.25f);
    }
}

// ---------------------------------------------------------------------------
// Head GEMM split-K (28 splits x 7 chunks). Block 64 rois x 128 oc. Grid (6,28).
__global__ __launch_bounds__(256) void head_gemm_mfma(
    const u16* __restrict__ rf, const u16* __restrict__ wtHt,
    float* __restrict__ Gpart)
{
    __shared__ __align__(16) u16 As[64 * 40];
    __shared__ __align__(16) u16 Bs[128 * 40];
    const int tid = threadIdx.x;
    const int rb = blockIdx.x >> 1, ob = blockIdx.x & 1;
    const int split = blockIdx.y;
    const int lane = tid & 63, wid = tid >> 6;
    const int q = lane >> 4, m16 = lane & 15;
    const int wr = wid & 1, wo = wid >> 1;

    const int arl = tid >> 2, aqd = tid & 3;
    const u16* abase = rf + (long long)(rb * 64 + arl) * KRF + aqd * 8;
    const int bol0 = tid >> 2, bqd = tid & 3;
    const u16* bbase0 = wtHt + (long long)(ob * 128 + bol0) * KRF + bqd * 8;
    const u16* bbase1 = bbase0 + 64LL * KRF;

    f32x4 acc[2][4];
    #pragma unroll
    for (int i = 0; i < 2; ++i)
        #pragma unroll
        for (int j = 0; j < 4; ++j) acc[i][j] = (f32x4){0.f, 0.f, 0.f, 0.f};

    int k0 = split * CPS * 32;
    bf16x8 ra = *(const bf16x8*)(abase + k0);
    bf16x8 rb0 = *(const bf16x8*)(bbase0 + k0);
    bf16x8 rb1 = *(const bf16x8*)(bbase1 + k0);
    for (int cch = 0; cch < CPS; ++cch) {
        __syncthreads();
        *(bf16x8*)&As[arl * 40 + aqd * 8] = ra;
        *(bf16x8*)&Bs[bol0 * 40 + bqd * 8] = rb0;
        *(bf16x8*)&Bs[(64 + bol0) * 40 + bqd * 8] = rb1;
        __syncthreads();
        if (cch < CPS - 1) {
            int kn = k0 + (cch + 1) * 32;
            ra  = *(const bf16x8*)(abase + kn);
            rb0 = *(const bf16x8*)(bbase0 + kn);
            rb1 = *(const bf16x8*)(bbase1 + kn);
        }
        bf16x8 a[2], bb[4];
        #pragma unroll
        for (int rt = 0; rt < 2; ++rt)
            a[rt] = *(const bf16x8*)&As[(wr * 32 + rt * 16 + m16) * 40 + q * 8];
        #pragma unroll
        for (int ot = 0; ot < 4; ++ot)
            bb[ot] = *(const bf16x8*)&Bs[(wo * 64 + ot * 16 + m16) * 40 + q * 8];
        #pragma unroll
        for (int rt = 0; rt < 2; ++rt)
            #pragma unroll
            for (int ot = 0; ot < 4; ++ot)
                acc[rt][ot] = __builtin_amdgcn_mfma_f32_16x16x32_bf16(a[rt], bb[ot], acc[rt][ot], 0, 0, 0);
    }
    #pragma unroll
    for (int rt = 0; rt < 2; ++rt)
        #pragma unroll
        for (int ot = 0; ot < 4; ++ot) {
            int oc = ob * 128 + wo * 64 + ot * 16 + m16;
            #pragma unroll
            for (int rg = 0; rg < 4; ++rg) {
                int roi = rb * 64 + wr * 32 + rt * 16 + q * 4 + rg;
                Gpart[((long long)split * NROI + roi) * 256 + oc] = acc[rt][ot][rg];
            }
        }
}

// ---------------------------------------------------------------------------
// Fused tail: Gpart reduction + pair geometry + build_X + fc6 + fc7 + cls.
#define PHS 272
__global__ __launch_bounds__(256) void pair_head(
    const float* __restrict__ Gpart, const float* __restrict__ d1,
    const float* __restrict__ d2, const float* __restrict__ wsum4,
    const float* __restrict__ hb,
    const u16* __restrict__ w6, const float* __restrict__ b6,
    const u16* __restrict__ w7, const float* __restrict__ b7,
    const float* __restrict__ cw, const float* __restrict__ cb,
    float* __restrict__ scores, float* __restrict__ labels,
    float* __restrict__ valid)
{
    __shared__ __align__(16) u16 bufA[64 * PHS];
    __shared__ __align__(16) u16 bufB[64 * PHS];
    __shared__ float Gs[2][256];
    __shared__ float ps[64][4];
    __shared__ float clw[256];

    const int tid = threadIdx.x;
    const int p0 = blockIdx.x * 64;
    const int r0 = p0 / MM;
    const int lane = tid & 63, w = tid >> 6;
    const int q = lane >> 4, m16 = lane & 15;

    clw[tid] = cw[tid];
    #pragma unroll
    for (int l = 0; l < 2; ++l) {
        int idx = tid + l * 256;
        int rr = idx >> 8, col = idx & 255;
        int roi = min(r0 + rr, NROI - 1);
        float s = 0.f;
        #pragma unroll
        for (int sp = 0; sp < SPLITS; ++sp)
            s += Gpart[((long long)sp * NROI + roi) * 256 + col];
        Gs[rr][col] = s;
    }
    if (tid < 64) {
        int pair = p0 + tid;
        int b = pair / (MM * MM); int rem = pair % (MM * MM);
        int m1 = rem / MM, m2 = rem % MM;
        const float* rA = d1 + (long long)(b * MM + m1) * 10;
        const float* rB = d2 + (long long)(b * MM + m2) * 10;
        float v1 = rA[0], id1 = rA[1], cxa = rA[2], cya = rA[3], wa = rA[4], ha = rA[5];
        float v2 = rB[0], id2 = rB[1], cxb = rB[2], cyb = rB[3], wb = rB[4], hbv = rB[5];
        const float eps = 1e-6f;
        float ax1 = cxa - wa * 0.5f, ay1 = cya - ha * 0.5f;
        float ax2 = ax1 + wa,        ay2 = ay1 + ha;
        float bx1 = cxb - wb * 0.5f, by1 = cyb - hbv * 0.5f;
        float bx2 = bx1 + wb,        by2 = by1 + hbv;
        float ccx1 = (ax1 + ax2) * 0.5f, ccy1 = (ay1 + ay2) * 0.5f;
        float ww1 = fmaxf(ax2 - ax1, eps), hh1 = fmaxf(ay2 - ay1, eps);
        float ccx2 = (bx1 + bx2) * 0.5f, ccy2 = (by1 + by2) * 0.5f;
        float ww2 = fmaxf(bx2 - bx1, eps), hh2 = fmaxf(by2 - by1, eps);
        ps[tid][0] = (ccx2 - ccx1) / ww1;
        ps[tid][1] = (ccy2 - ccy1) / hh1;
        ps[tid][2] = logf(ww2 / ww1);
        ps[tid][3] = logf(hh2 / hh1);
        labels[pair] = (id1 == id2) ? 1.f : 0.f;
        valid[pair]  = (v1 != -1.f && v2 != -1.f) ? 1.f : 0.f;
    }
    __syncthreads();

    #pragma unroll
    for (int it = 0; it < 16; ++it) {
        int idx = tid + it * 256;
        int px = idx >> 6, o4 = (idx & 63) * 4;
        int rl = (p0 + px) / MM - r0;
        f32x4 g = *(const f32x4*)&Gs[rl][o4];
        f32x4 hv = *(const f32x4*)&hb[o4];
        f32x4 p4 = *(const f32x4*)&ps[px][0];
        u16x4 pk;
        #pragma unroll
        for (int j = 0; j < 4; ++j) {
            f32x4 w4 = *(const f32x4*)&wsum4[(o4 + j) * 4];
            float v = g[j] + hv[j] + p4[0] * w4[0] + p4[1] * w4[1] + p4[2] * w4[2] + p4[3] * w4[3];
            pk[j] = f2bf(v);
        }
        *(u16x4*)&bufA[px * PHS + o4] = pk;
    }
    __syncthreads();

    #pragma unroll
    for (int layer = 0; layer < 2; ++layer) {
        const u16* wgt = layer ? w7 : w6;
        const float* bs = layer ? b7 : b6;
        const u16* src = layer ? bufB : bufA;
        u16* dst = layer ? bufA : bufB;
        f32x4 acc[4][4];
        #pragma unroll
        for (int i = 0; i < 4; ++i)
            #pragma unroll
            for (int j = 0; j < 4; ++j) acc[i][j] = (f32x4){0.f, 0.f, 0.f, 0.f};
        #pragma unroll
        for (int kc = 0; kc < 8; ++kc) {
            bf16x8 a[4], bb[4];
            #pragma unroll
            for (int i = 0; i < 4; ++i)
                a[i] = *(const bf16x8*)&wgt[(w * 64 + i * 16 + m16) * 256 + kc * 32 + q * 8];
            #pragma unroll
            for (int pt = 0; pt < 4; ++pt)
                bb[pt] = *(const bf16x8*)&src[(pt * 16 + m16) * PHS + kc * 32 + q * 8];
            #pragma unroll
            for (int i = 0; i < 4; ++i)
                #pragma unroll
                for (int pt = 0; pt < 4; ++pt)
                    acc[i][pt] = __builtin_amdgcn_mfma_f32_16x16x32_bf16(a[i], bb[pt], acc[i][pt], 0, 0, 0);
        }
        #pragma unroll
        for (int i = 0; i < 4; ++i) {
            int oc4 = w * 64 + i * 16 + q * 4;
            f32x4 bv = *(const f32x4*)(bs + oc4);
            #pragma unroll
            for (int pt = 0; pt < 4; ++pt) {
                int px = pt * 16 + m16;
                f32x4 dd = acc[i][pt];
                u16x4 pk;
                #pragma unroll
                for (int rg = 0; rg < 4; ++rg)
                    pk[rg] = f2bf(fmaxf(dd[rg] + bv[rg], 0.f));
                *(u16x4*)&dst[px * PHS + oc4] = pk;
            }
        }
        __syncthreads();
    }

    {
        int px = tid >> 2, qq = tid & 3;
        float acc = 0.f;
        #pragma unroll
        for (int k8 = 0; k8 < 8; ++k8) {
            bf16x8 hv = *(const bf16x8*)&bufA[px * PHS + qq * 64 + k8 * 8];
            #pragma unroll
            for (int e = 0; e < 8; ++e)
                acc += b2f((u16)hv[e]) * clw[qq * 64 + k8 * 8 + e];
        }
        acc += __shfl_xor(acc, 1, 64);
        acc += __shfl_xor(acc, 2, 64);
        if (qq == 0) scores[p0 + px] = acc + cb[0];
    }
}

// ---------------------------------------------------------------------------
extern "C" void kernel_launch(void* const* d_in, const int* in_sizes, int n_in,
                              void* d_out, int out_size, void* d_ws, size_t ws_size,
                              hipStream_t stream) {
    const float* corr   = (const float*)d_in[0];
    const float* det1   = (const float*)d_in[2];
    const float* det2   = (const float*)d_in[3];
    const float* c1w    = (const float*)d_in[4];
    const float* c1b    = (const float*)d_in[5];
    const float* c2w    = (const float*)d_in[6];
    const float* c2b    = (const float*)d_in[7];
    const float* c3w    = (const float*)d_in[8];
    const float* c3b    = (const float*)d_in[9];
    const float* hw     = (const float*)d_in[10];
    const float* hbias  = (const float*)d_in[11];
    const float* f6w    = (const float*)d_in[12];
    const float* f6b    = (const float*)d_in[13];
    const float* f7w    = (const float*)d_in[14];
    const float* f7b    = (const float*)d_in[15];
    const float* clsw   = (const float*)d_in[16];
    const float* clsb   = (const float*)d_in[17];
    float* out = (float*)d_out;

    char* base = (char*)d_ws;
    auto alloc = [&](size_t bytes) { char* p = base; base += (bytes + 255) & ~(size_t)255; return p; };

    const size_t ACTP_BYTES = (size_t)NB * 98 * 98 * 256 * 2;
    u16*   act1p = (u16*)  alloc(ACTP_BYTES);
    u16*   act2p = (u16*)  alloc(ACTP_BYTES);
    u16*   rel   = (u16*)  alloc((size_t)NB * PIX * 128 * 2);
    u16*   wt1f  = (u16*)  alloc((size_t)90112 * 2);
    u16*   wt2f  = (u16*)  alloc((size_t)2 * 16 * CWSTG * 2);
    u16*   wt3f  = (u16*)  alloc((size_t)16 * CWSTG * 2);
    u16*   wtHt  = (u16*)  alloc((size_t)256 * KRF * 2);
    u16*   w6c   = (u16*)  alloc(256 * 256 * 2);
    u16*   w7c   = (u16*)  alloc(256 * 256 * 2);
    float* wsum4 = (float*)alloc(256 * 4 * 4);
    u16*   rf    = (u16*)  alloc((size_t)NROI * KRF * 2);
    float* Gpart = (float*)alloc((size_t)SPLITS * NROI * 256 * 4);

    float* scores_out = out;
    float* labels_out = out + NPAIR;
    float* valid_out  = out + 2 * NPAIR;

    prep_v2<<<732, 256, 0, stream>>>(c1w, c2w, c3w, hw, f6w, f7w,
                                     wt1f, wt2f, wt3f, wtHt, w6c, w7c, wsum4,
                                     act1p, act2p);
    conv1_v3<<<dim3(144, NB), 256, 0, stream>>>(corr, wt1f, c1b, act1p);
    conv3x3_v4<256, true><<<dim3(36, 2, NB), 256, 0, stream>>>(act1p, wt2f, c2b, act2p);
    conv3x3_v4<128, false><<<dim3(36, 1, NB), 256, 0, stream>>>(act2p, wt3f, c3b, rel);
    roi_align_cl<<<NROI, 256, 0, stream>>>(rel, det1, rf);
    head_gemm_mfma<<<dim3(6, SPLITS), 256, 0, stream>>>(rf, wtHt, Gpart);
    pair_head<<<144, 256, 0, stream>>>(Gpart, det1, det2, wsum4, hbias,
                                       w6c, f6b, w7c, f7b, clsw, clsb,
                                       scores_out, labels_out, valid_out);
}

// Round 9
// 270.081 us; speedup vs baseline: 1.0699x; 1.0699x over previous
//
#include <hip/hip_runtime.h>
#include <hip/hip_bf16.h>

#define NB    4
#define HH    96
#define WW    96
#define PIX   9216
#define C0    324
#define MM    48
#define NROI  192
#define NPAIR 9216
#define KHEAD 6468
#define KRF   6272
#define SPLITS 28
#define CPS    7     // 28*7*32 = 6272

// conv2/3 weight stage: 9 taps x 4 octiles x 64 lanes x 8 = 18432 elems per (ocb,icb)
#define CWSTG 18432

typedef unsigned short u16;
typedef __attribute__((ext_vector_type(8))) short bf16x8;
typedef __attribute__((ext_vector_type(4))) float f32x4;
typedef __attribute__((ext_vector_type(16))) float f32x16;
typedef __attribute__((ext_vector_type(4))) unsigned short u16x4;
typedef __attribute__((ext_vector_type(8))) unsigned short u16x8;
typedef __attribute__((ext_vector_type(4))) int i32x4;

__device__ __forceinline__ u16 f2bf(float f) {
    __hip_bfloat16 h = __float2bfloat16(f);
    union { __hip_bfloat16 h; u16 u; } c; c.h = h; return c.u;
}
__device__ __forceinline__ float b2f(u16 u) {
    union { unsigned int i; float f; } c; c.i = ((unsigned int)u) << 16; return c.f;
}

// ---------------------------------------------------------------------------
// Merged prep + halo-zero (unchanged — verified layouts).
__global__ __launch_bounds__(256) void prep_v2(
    const float* __restrict__ c1w, const float* __restrict__ c2w,
    const float* __restrict__ c3w, const float* __restrict__ hw,
    const float* __restrict__ f6w, const float* __restrict__ f7w,
    u16* __restrict__ wt1f, u16* __restrict__ wt2f, u16* __restrict__ wt3f,
    u16* __restrict__ wtHt, u16* __restrict__ w6c, u16* __restrict__ w7c,
    float* __restrict__ wsum4, u16* __restrict__ a1, u16* __restrict__ a2)
{
    __shared__ u16 L[18432];
    const int blk = blockIdx.x, tid = threadIdx.x;

    if (blk < 8) {
        const int ot = blk;
        const float* src = c1w + (size_t)ot * 32 * C0;
        for (int it = 0; it < 11; ++it) {
            int i = tid + it * 256;
            if (i < 2592) {
                float4 v = *(const float4*)(src + i * 4);
                int n = i / 81, k4 = (i % 81) * 4;
                L[n * 324 + k4 + 0] = f2bf(v.x);
                L[n * 324 + k4 + 1] = f2bf(v.y);
                L[n * 324 + k4 + 2] = f2bf(v.z);
                L[n * 324 + k4 + 3] = f2bf(v.w);
            }
        }
        __syncthreads();
        for (int it = 0; it < 6; ++it) {
            int v = tid + it * 256;
            if (v >= 1408) break;
            int ks = v >> 6, lane = v & 63;
            int n = lane & 31, half = lane >> 5;
            u16x8 pk;
            #pragma unroll
            for (int j = 0; j < 8; ++j) {
                int k = ks * 16 + half * 8 + j;
                pk[j] = (k < C0) ? L[n * 324 + k] : (u16)0;
            }
            *(u16x8*)&wt1f[((ks * 8 + ot) * 64 + lane) * 8] = pk;
        }
    } else if (blk < 56) {
        const bool is2 = blk < 40;
        const int b8 = is2 ? (blk - 8) : (blk - 40);
        const int oc8 = b8 * 8;
        const int ocb = oc8 >> 7;
        const int ot = (oc8 >> 5) & 3;
        const int nb = oc8 & 31;
        const float* src = (is2 ? c2w : c3w) + (size_t)oc8 * 2304;
        u16* dst = is2 ? wt2f : wt3f;
        for (int it = 0; it < 18; ++it) {
            int i = tid + it * 256;
            float4 v = *(const float4*)(src + i * 4);
            int n = i / 576, t4 = (i % 576) * 4;
            L[n * 2304 + t4 + 0] = f2bf(v.x);
            L[n * 2304 + t4 + 1] = f2bf(v.y);
            L[n * 2304 + t4 + 2] = f2bf(v.z);
            L[n * 2304 + t4 + 3] = f2bf(v.w);
        }
        __syncthreads();
        for (int it = 0; it < 9; ++it) {
            int v = tid + it * 256;
            int o8 = v & 7; int rest = v >> 3;
            int half = rest & 1; rest >>= 1;
            int tap = rest % 9; int icb = rest / 9;
            int lane = half * 32 + nb + o8;
            u16x8 pk;
            #pragma unroll
            for (int j = 0; j < 8; ++j) {
                int ic = icb * 16 + half * 8 + j;
                pk[j] = L[o8 * 2304 + ic * 9 + tap];
            }
            size_t dest = ((((size_t)(ocb * 16 + icb) * 9 + tap) * 4 + ot) * 64 + lane) * 8;
            *(u16x8*)&dst[dest] = pk;
        }
    } else if (blk < 312) {
        const int oc = blk - 56;
        const float* src = hw + (size_t)oc * KHEAD;
        for (int it = 0; it < 7; ++it) {
            int i = tid + it * 256;
            if (i < 1617) {
                float4 v = *(const float4*)(src + i * 4);
                L[i * 4 + 0] = f2bf(v.x);
                L[i * 4 + 1] = f2bf(v.y);
                L[i * 4 + 2] = f2bf(v.z);
                L[i * 4 + 3] = f2bf(v.w);
            }
        }
        if (tid < 4) {
            const float* p = src + (128 + tid) * 49;
            float s = 0.f;
            #pragma unroll
            for (int t = 0; t < 49; ++t) s += p[t];
            wsum4[oc * 4 + tid] = s;
        }
        __syncthreads();
        for (int it = 0; it < 4; ++it) {
            int v = tid + it * 256;
            if (v >= 784) break;
            u16x8 pk;
            #pragma unroll
            for (int j = 0; j < 8; ++j) {
                int r = v * 8 + j;
                int s = r >> 7, c = r & 127;
                pk[j] = L[c * 49 + s];
            }
            *(u16x8*)&wtHt[(size_t)oc * KRF + v * 8] = pk;
        }
    } else if (blk < 344) {
        const bool is6 = blk < 328;
        const int b = is6 ? (blk - 312) : (blk - 328);
        const float* src = (is6 ? f6w : f7w) + (size_t)(b * 256 + tid) * 16;
        u16* dst = (is6 ? w6c : w7c) + (size_t)(b * 256 + tid) * 16;
        u16x8 pk0, pk1;
        #pragma unroll
        for (int h = 0; h < 2; ++h) {
            float4 v0 = *(const float4*)(src + h * 8);
            float4 v1 = *(const float4*)(src + h * 8 + 4);
            u16x8 pk;
            pk[0] = f2bf(v0.x); pk[1] = f2bf(v0.y); pk[2] = f2bf(v0.z); pk[3] = f2bf(v0.w);
            pk[4] = f2bf(v1.x); pk[5] = f2bf(v1.y); pk[6] = f2bf(v1.z); pk[7] = f2bf(v1.w);
            if (h == 0) pk0 = pk; else pk1 = pk;
        }
        *(u16x8*)(dst + 0) = pk0;
        *(u16x8*)(dst + 8) = pk1;
    } else {
        int idx = (blk - 344) * 256 + tid;
        int c8 = idx & 31;
        int t = idx >> 5;
        int h = t % 388, img = t / 388;
        u16* base = (img & 4) ? a2 : a1;
        int b = img & 3;
        int y, x;
        if (h < 98)       { y = 0;  x = h; }
        else if (h < 196) { y = 97; x = h - 98; }
        else { int r = (h - 196) >> 1; x = ((h - 196) & 1) * 97; y = 1 + r; }
        long long off = (((long long)(b * 98 + y)) * 98 + x) * 256 + c8 * 8;
        i32x4 z = {0, 0, 0, 0};
        *(i32x4*)(base + off) = z;
    }
}

// ---------------------------------------------------------------------------
// conv1 v4: one-shot transpose of all K into LDS (92 KB), one barrier, then
// 88 MFMAs/wave with A-fragments from global (L2-resident, frag-ready layout).
// 512 threads = 8 waves (one 32-oc tile each), 128 px/block. Grid (72, 4).
__global__ __launch_bounds__(512) void conv1_v4(
    const float* __restrict__ corr, const u16* __restrict__ wf,
    const float* __restrict__ bias, u16* __restrict__ outp)
{
    __shared__ __align__(16) u16 Bs[128 * 360];
    const int tid = threadIdx.x;
    const int b = blockIdx.y;
    const int p0 = blockIdx.x * 128;
    const int lane = tid & 63, wid = tid >> 6;
    const int n = lane & 31, half = lane >> 5;

    // transpose: 5632 chunks (44 kgroups x 128 px), 11 per thread
    #pragma unroll
    for (int it = 0; it < 11; ++it) {
        int chunk = it * 512 + tid;
        int kg = chunk >> 7, px = chunk & 127;
        u16x8 pk;
        #pragma unroll
        for (int j = 0; j < 8; ++j) {
            int k = kg * 8 + j;
            float v = (k < C0) ? corr[((long long)(b * C0 + k)) * PIX + p0 + px] : 0.f;
            pk[j] = f2bf(v);
        }
        *(u16x8*)&Bs[px * 360 + kg * 8] = pk;
    }
    __syncthreads();

    f32x16 acc[4];
    #pragma unroll
    for (int i = 0; i < 4; ++i)
        #pragma unroll
        for (int e = 0; e < 16; ++e) acc[i][e] = 0.f;

    #pragma unroll
    for (int ks = 0; ks < 22; ++ks) {
        bf16x8 A = *(const bf16x8*)(wf + (size_t)((ks * 8 + wid) * 64 + lane) * 8);
        #pragma unroll
        for (int nt = 0; nt < 4; ++nt) {
            bf16x8 B = *(const bf16x8*)&Bs[(nt * 32 + n) * 360 + ks * 16 + half * 8];
            acc[nt] = __builtin_amdgcn_mfma_f32_32x32x16_bf16(A, B, acc[nt], 0, 0, 0);
        }
    }
    #pragma unroll
    for (int nt = 0; nt < 4; ++nt) {
        int px = p0 + nt * 32 + n;
        int y = px / 96, x = px % 96;
        long long obase = (((long long)(b * 98 + y + 1)) * 98 + x + 1) * 256;
        f32x16 d = acc[nt];
        #pragma unroll
        for (int r2 = 0; r2 < 4; ++r2) {
            int oc4 = wid * 32 + r2 * 8 + half * 4;
            f32x4 bv = *(const f32x4*)(bias + oc4);
            u16x4 pk;
            #pragma unroll
            for (int g = 0; g < 4; ++g) pk[g] = f2bf(fmaxf(d[r2 * 4 + g] + bv[g], 0.f));
            *(u16x4*)(outp + obase + oc4) = pk;
        }
    }
}

// ---------------------------------------------------------------------------
// conv3x3 v5: full-width tiles (ROWS x 96), block = 128 oc, 4 waves = 4 oc-tiles
// of 32. Double-buffered Ws/Hs -> ONE barrier per 16-ic stage.
// conv2: ROWS=3 -> grid (32,2,4) = 256 (1 block/CU exactly).
// conv3: ROWS=2 -> grid (48,1,4) = 192.
template<int ROWS, bool PADOUT, int COUT>
__global__ __launch_bounds__(256) void conv3x3_v5(
    const u16* __restrict__ inp, const u16* __restrict__ wf,
    const float* __restrict__ bias, u16* __restrict__ outp)
{
    const int HR  = ROWS + 2;
    const int NHP = HR * 98;
    __shared__ __align__(16) u16 Ws[2][CWSTG];
    __shared__ __align__(16) u16 Hs[2][NHP * 24];
    const int tid = threadIdx.x;
    const int b = blockIdx.z;
    const int y0 = blockIdx.x * ROWS;
    const int lane = tid & 63, wid = tid >> 6;   // wid = oc tile
    const int n = lane & 31, half = lane >> 5;

    const u16* wsrc = wf + (size_t)blockIdx.y * 16 * CWSTG;
    const int hp0 = tid, hp1 = tid + 256;
    const bool hv1 = hp1 < NHP;
    const int hr0 = hp0 / 98, hc0 = hp0 % 98;
    const int hr1 = hp1 / 98, hc1 = hp1 % 98;
    const u16* hsrc0 = inp + (((size_t)(b * 98 + y0 + hr0)) * 98 + hc0) * 256;
    const u16* hsrc1 = inp + (((size_t)(b * 98 + y0 + hr1)) * 98 + hc1) * 256;

    f32x16 acc[3 * ROWS];
    #pragma unroll
    for (int i = 0; i < 3 * ROWS; ++i)
        #pragma unroll
        for (int e = 0; e < 16; ++e) acc[i][e] = 0.f;

    // prologue: stage icb=0 into buffer 0
    {
        #pragma unroll
        for (int it = 0; it < 9; ++it)
            *(bf16x8*)&Ws[0][(it * 256 + tid) * 8] = *(const bf16x8*)(wsrc + (size_t)(it * 256 + tid) * 8);
        bf16x8 a0 = *(const bf16x8*)hsrc0, a1 = *(const bf16x8*)(hsrc0 + 8);
        *(bf16x8*)&Hs[0][hp0 * 24]     = a0;
        *(bf16x8*)&Hs[0][hp0 * 24 + 8] = a1;
        if (hv1) {
            bf16x8 b0 = *(const bf16x8*)hsrc1, b1 = *(const bf16x8*)(hsrc1 + 8);
            *(bf16x8*)&Hs[0][hp1 * 24]     = b0;
            *(bf16x8*)&Hs[0][hp1 * 24 + 8] = b1;
        }
    }

    for (int icb = 0; icb < 16; ++icb) {
        const int cur = icb & 1;
        // prefetch next stage into registers (issued before the barrier)
        bf16x8 wreg[9];
        bf16x8 ha0, ha1, hb0, hb1;
        if (icb < 15) {
            const u16* wn = wsrc + (size_t)(icb + 1) * CWSTG;
            #pragma unroll
            for (int it = 0; it < 9; ++it)
                wreg[it] = *(const bf16x8*)(wn + (size_t)(it * 256 + tid) * 8);
            const u16* p0n = hsrc0 + (icb + 1) * 16;
            ha0 = *(const bf16x8*)p0n; ha1 = *(const bf16x8*)(p0n + 8);
            if (hv1) {
                const u16* p1n = hsrc1 + (icb + 1) * 16;
                hb0 = *(const bf16x8*)p1n; hb1 = *(const bf16x8*)(p1n + 8);
            }
        }
        __syncthreads();
        // write next-stage buffers (idle buffer, safe after barrier)
        if (icb < 15) {
            const int nxt = 1 - cur;
            #pragma unroll
            for (int it = 0; it < 9; ++it)
                *(bf16x8*)&Ws[nxt][(it * 256 + tid) * 8] = wreg[it];
            *(bf16x8*)&Hs[nxt][hp0 * 24]     = ha0;
            *(bf16x8*)&Hs[nxt][hp0 * 24 + 8] = ha1;
            if (hv1) {
                *(bf16x8*)&Hs[nxt][hp1 * 24]     = hb0;
                *(bf16x8*)&Hs[nxt][hp1 * 24 + 8] = hb1;
            }
        }
        // compute current stage
        bf16x8 A[9];
        #pragma unroll
        for (int tap = 0; tap < 9; ++tap)
            A[tap] = *(const bf16x8*)&Ws[cur][((tap * 4 + wid) * 64 + lane) * 8];
        #pragma unroll
        for (int cf = 0; cf < 3; ++cf) {
            bf16x8 B[HR][3];
            #pragma unroll
            for (int rh = 0; rh < HR; ++rh)
                #pragma unroll
                for (int dx = 0; dx < 3; ++dx)
                    B[rh][dx] = *(const bf16x8*)&Hs[cur][((rh * 98) + cf * 32 + dx + n) * 24 + half * 8];
            #pragma unroll
            for (int tap = 0; tap < 9; ++tap) {
                const int dy = tap / 3, dx = tap % 3;
                #pragma unroll
                for (int ro = 0; ro < ROWS; ++ro)
                    acc[cf * ROWS + ro] = __builtin_amdgcn_mfma_f32_32x32x16_bf16(
                        A[tap], B[ro + dy][dx], acc[cf * ROWS + ro], 0, 0, 0);
            }
        }
    }
    // epilogue
    #pragma unroll
    for (int cf = 0; cf < 3; ++cf) {
        #pragma unroll
        for (int ro = 0; ro < ROWS; ++ro) {
            int y = y0 + ro;
            int x = cf * 32 + n;
            f32x16 d = acc[cf * ROWS + ro];
            long long obase;
            if (PADOUT) obase = (((long long)(b * 98 + y + 1)) * 98 + x + 1) * COUT;
            else        obase = (((long long)(b * 96 + y)) * 96 + x) * COUT;
            #pragma unroll
            for (int r2 = 0; r2 < 4; ++r2) {
                int oc4 = blockIdx.y * 128 + wid * 32 + r2 * 8 + half * 4;
                f32x4 bv = *(const f32x4*)(bias + oc4);
                u16x4 pk;
                #pragma unroll
                for (int g = 0; g < 4; ++g) pk[g] = f2bf(fmaxf(d[r2 * 4 + g] + bv[g], 0.f));
                *(u16x4*)(outp + obase + oc4) = pk;
                (void)0;
                // advance r2 row group
                d = d; // no-op
                oc4 += 0;
                // store done above
                // (next r2 handled by loop)
                // note: oc4 recomputed each r2
                // ---
                continue;
            }
        }
    }
}

// ---------------------------------------------------------------------------
// ROI align: rel [4][96][96][128] bf16 -> rf [192][6272] bf16 (k' = s*128+c)
__global__ __launch_bounds__(256) void roi_align_cl(
    const u16* __restrict__ rel, const float* __restrict__ det1,
    u16* __restrict__ rf)
{
    const int roi = blockIdx.x, tid = threadIdx.x;
    const int c = tid & 127, sb = tid >> 7;
    const int b = roi / MM, m = roi % MM;
    const float* d = det1 + (long long)(b * MM + m) * 10;
    float cx = d[2], cy = d[3], w = d[4], h = d[5];
    float x1f = cx - w * 0.5f, y1f = cy - h * 0.5f;
    float x1 = x1f * 0.125f, y1 = y1f * 0.125f;
    float x2 = (x1f + w) * 0.125f, y2 = (y1f + h) * 0.125f;
    float bh = (y2 - y1) * (1.f / 7.f), bw = (x2 - x1) * (1.f / 7.f);
    const u16* fb = rel + (long long)b * PIX * 128 + c;
    for (int s = sb; s < 49; s += 2) {
        int i = s / 7, j = s % 7;
        float sum = 0.f;
        #pragma unroll
        for (int di = 0; di < 2; ++di) {
            float y = y1 + ((float)(2 * i + di) + 0.5f) * 0.5f * bh;
            y = fminf(fmaxf(y, 0.f), 95.f);
            int yy0 = (int)floorf(y);
            int yy1 = min(yy0 + 1, 95);
            float wy = y - (float)yy0;
            #pragma unroll
            for (int dj = 0; dj < 2; ++dj) {
                float x = x1 + ((float)(2 * j + dj) + 0.5f) * 0.5f * bw;
                x = fminf(fmaxf(x, 0.f), 95.f);
                int xx0 = (int)floorf(x);
                int xx1 = min(xx0 + 1, 95);
                float wx = x - (float)xx0;
                float f00 = b2f(fb[((long long)yy0 * 96 + xx0) * 128]);
                float f01 = b2f(fb[((long long)yy0 * 96 + xx1) * 128]);
                float f10 = b2f(fb[((long long)yy1 * 96 + xx0) * 128]);
                float f11 = b2f(fb[((long long)yy1 * 96 + xx1) * 128]);
                sum += f00 * (1.f - wy) * (1.f - wx) + f01 * (1.f - wy) * wx
                     + f10 * wy * (1.f - wx) + f11 * wy * wx;
            }
        }
        rf[(long long)roi * KRF + s * 128 + c] = f2bf(sum * 0.25f);
    }
}

// ---------------------------------------------------------------------------
// Head GEMM split-K (28 splits x 7 chunks). Block 64 rois x 128 oc. Grid (6,28).
__global__ __launch_bounds__(256) void head_gemm_mfma(
    const u16* __restrict__ rf, const u16* __restrict__ wtHt,
    float* __restrict__ Gpart)
{
    __shared__ __align__(16) u16 As[64 * 40];
    __shared__ __align__(16) u16 Bs[128 * 40];
    const int tid = threadIdx.x;
    const int rb = blockIdx.x >> 1, ob = blockIdx.x & 1;
    const int split = blockIdx.y;
    const int lane = tid & 63, wid = tid >> 6;
    const int q = lane >> 4, m16 = lane & 15;
    const int wr = wid & 1, wo = wid >> 1;

    const int arl = tid >> 2, aqd = tid & 3;
    const u16* abase = rf + (long long)(rb * 64 + arl) * KRF + aqd * 8;
    const int bol0 = tid >> 2, bqd = tid & 3;
    const u16* bbase0 = wtHt + (long long)(ob * 128 + bol0) * KRF + bqd * 8;
    const u16* bbase1 = bbase0 + 64LL * KRF;

    f32x4 acc[2][4];
    #pragma unroll
    for (int i = 0; i < 2; ++i)
        #pragma unroll
        for (int j = 0; j < 4; ++j) acc[i][j] = (f32x4){0.f, 0.f, 0.f, 0.f};

    int k0 = split * CPS * 32;
    bf16x8 ra = *(const bf16x8*)(abase + k0);
    bf16x8 rb0 = *(const bf16x8*)(bbase0 + k0);
    bf16x8 rb1 = *(const bf16x8*)(bbase1 + k0);
    for (int cch = 0; cch < CPS; ++cch) {
        __syncthreads();
        *(bf16x8*)&As[arl * 40 + aqd * 8] = ra;
        *(bf16x8*)&Bs[bol0 * 40 + bqd * 8] = rb0;
        *(bf16x8*)&Bs[(64 + bol0) * 40 + bqd * 8] = rb1;
        __syncthreads();
        if (cch < CPS - 1) {
            int kn = k0 + (cch + 1) * 32;
            ra  = *(const bf16x8*)(abase + kn);
            rb0 = *(const bf16x8*)(bbase0 + kn);
            rb1 = *(const bf16x8*)(bbase1 + kn);
        }
        bf16x8 a[2], bb[4];
        #pragma unroll
        for (int rt = 0; rt < 2; ++rt)
            a[rt] = *(const bf16x8*)&As[(wr * 32 + rt * 16 + m16) * 40 + q * 8];
        #pragma unroll
        for (int ot = 0; ot < 4; ++ot)
            bb[ot] = *(const bf16x8*)&Bs[(wo * 64 + ot * 16 + m16) * 40 + q * 8];
        #pragma unroll
        for (int rt = 0; rt < 2; ++rt)
            #pragma unroll
            for (int ot = 0; ot < 4; ++ot)
                acc[rt][ot] = __builtin_amdgcn_mfma_f32_16x16x32_bf16(a[rt], bb[ot], acc[rt][ot], 0, 0, 0);
    }
    #pragma unroll
    for (int rt = 0; rt < 2; ++rt)
        #pragma unroll
        for (int ot = 0; ot < 4; ++ot) {
            int oc = ob * 128 + wo * 64 + ot * 16 + m16;
            #pragma unroll
            for (int rg = 0; rg < 4; ++rg) {
                int roi = rb * 64 + wr * 32 + rt * 16 + q * 4 + rg;
                Gpart[((long long)split * NROI + roi) * 256 + oc] = acc[rt][ot][rg];
            }
        }
}

// ---------------------------------------------------------------------------
// Fused tail: Gpart reduction + pair geometry + build_X + fc6 + fc7 + cls.
#define PHS 272
__global__ __launch_bounds__(256) void pair_head(
    const float* __restrict__ Gpart, const float* __restrict__ d1,
    const float* __restrict__ d2, const float* __restrict__ wsum4,
    const float* __restrict__ hb,
    const u16* __restrict__ w6, const float* __restrict__ b6,
    const u16* __restrict__ w7, const float* __restrict__ b7,
    const float* __restrict__ cw, const float* __restrict__ cb,
    float* __restrict__ scores, float* __restrict__ labels,
    float* __restrict__ valid)
{
    __shared__ __align__(16) u16 bufA[64 * PHS];
    __shared__ __align__(16) u16 bufB[64 * PHS];
    __shared__ float Gs[2][256];
    __shared__ float ps[64][4];
    __shared__ float clw[256];

    const int tid = threadIdx.x;
    const int p0 = blockIdx.x * 64;
    const int r0 = p0 / MM;
    const int lane = tid & 63, w = tid >> 6;
    const int q = lane >> 4, m16 = lane & 15;

    clw[tid] = cw[tid];
    #pragma unroll
    for (int l = 0; l < 2; ++l) {
        int idx = tid + l * 256;
        int rr = idx >> 8, col = idx & 255;
        int roi = min(r0 + rr, NROI - 1);
        float s = 0.f;
        #pragma unroll
        for (int sp = 0; sp < SPLITS; ++sp)
            s += Gpart[((long long)sp * NROI + roi) * 256 + col];
        Gs[rr][col] = s;
    }
    if (tid < 64) {
        int pair = p0 + tid;
        int b = pair / (MM * MM); int rem = pair % (MM * MM);
        int m1 = rem / MM, m2 = rem % MM;
        const float* rA = d1 + (long long)(b * MM + m1) * 10;
        const float* rB = d2 + (long long)(b * MM + m2) * 10;
        float v1 = rA[0], id1 = rA[1], cxa = rA[2], cya = rA[3], wa = rA[4], ha = rA[5];
        float v2 = rB[0], id2 = rB[1], cxb = rB[2], cyb = rB[3], wb = rB[4], hbv = rB[5];
        const float eps = 1e-6f;
        float ax1 = cxa - wa * 0.5f, ay1 = cya - ha * 0.5f;
        float ax2 = ax1 + wa,        ay2 = ay1 + ha;
        float bx1 = cxb - wb * 0.5f, by1 = cyb - hbv * 0.5f;
        float bx2 = bx1 + wb,        by2 = by1 + hbv;
        float ccx1 = (ax1 + ax2) * 0.5f, ccy1 = (ay1 + ay2) * 0.5f;
        float ww1 = fmaxf(ax2 - ax1, eps), hh1 = fmaxf(ay2 - ay1, eps);
        float ccx2 = (bx1 + bx2) * 0.5f, ccy2 = (by1 + by2) * 0.5f;
        float ww2 = fmaxf(bx2 - bx1, eps), hh2 = fmaxf(by2 - by1, eps);
        ps[tid][0] = (ccx2 - ccx1) / ww1;
        ps[tid][1] = (ccy2 - ccy1) / hh1;
        ps[tid][2] = logf(ww2 / ww1);
        ps[tid][3] = logf(hh2 / hh1);
        labels[pair] = (id1 == id2) ? 1.f : 0.f;
        valid[pair]  = (v1 != -1.f && v2 != -1.f) ? 1.f : 0.f;
    }
    __syncthreads();

    #pragma unroll
    for (int it = 0; it < 16; ++it) {
        int idx = tid + it * 256;
        int px = idx >> 6, o4 = (idx & 63) * 4;
        int rl = (p0 + px) / MM - r0;
        f32x4 g = *(const f32x4*)&Gs[rl][o4];
        f32x4 hv = *(const f32x4*)&hb[o4];
        f32x4 p4 = *(const f32x4*)&ps[px][0];
        u16x4 pk;
        #pragma unroll
        for (int j = 0; j < 4; ++j) {
            f32x4 w4 = *(const f32x4*)&wsum4[(o4 + j) * 4];
            float v = g[j] + hv[j] + p4[0] * w4[0] + p4[1] * w4[1] + p4[2] * w4[2] + p4[3] * w4[3];
            pk[j] = f2bf(v);
        }
        *(u16x4*)&bufA[px * PHS + o4] = pk;
    }
    __syncthreads();

    #pragma unroll
    for (int layer = 0; layer < 2; ++layer) {
        const u16* wgt = layer ? w7 : w6;
        const float* bs = layer ? b7 : b6;
        const u16* src = layer ? bufB : bufA;
        u16* dst = layer ? bufA : bufB;
        f32x4 acc[4][4];
        #pragma unroll
        for (int i = 0; i < 4; ++i)
            #pragma unroll
            for (int j = 0; j < 4; ++j) acc[i][j] = (f32x4){0.f, 0.f, 0.f, 0.f};
        #pragma unroll
        for (int kc = 0; kc < 8; ++kc) {
            bf16x8 a[4], bb[4];
            #pragma unroll
            for (int i = 0; i < 4; ++i)
                a[i] = *(const bf16x8*)&wgt[(w * 64 + i * 16 + m16) * 256 + kc * 32 + q * 8];
            #pragma unroll
            for (int pt = 0; pt < 4; ++pt)
                bb[pt] = *(const bf16x8*)&src[(pt * 16 + m16) * PHS + kc * 32 + q * 8];
            #pragma unroll
            for (int i = 0; i < 4; ++i)
                #pragma unroll
                for (int pt = 0; pt < 4; ++pt)
                    acc[i][pt] = __builtin_amdgcn_mfma_f32_16x16x32_bf16(a[i], bb[pt], acc[i][pt], 0, 0, 0);
        }
        #pragma unroll
        for (int i = 0; i < 4; ++i) {
            int oc4 = w * 64 + i * 16 + q * 4;
            f32x4 bv = *(const f32x4*)(bs + oc4);
            #pragma unroll
            for (int pt = 0; pt < 4; ++pt) {
                int px = pt * 16 + m16;
                f32x4 dd = acc[i][pt];
                u16x4 pk;
                #pragma unroll
                for (int rg = 0; rg < 4; ++rg)
                    pk[rg] = f2bf(fmaxf(dd[rg] + bv[rg], 0.f));
                *(u16x4*)&dst[px * PHS + oc4] = pk;
            }
        }
        __syncthreads();
    }

    {
        int px = tid >> 2, qq = tid & 3;
        float acc = 0.f;
        #pragma unroll
        for (int k8 = 0; k8 < 8; ++k8) {
            bf16x8 hv = *(const bf16x8*)&bufA[px * PHS + qq * 64 + k8 * 8];
            #pragma unroll
            for (int e = 0; e < 8; ++e)
                acc += b2f((u16)hv[e]) * clw[qq * 64 + k8 * 8 + e];
        }
        acc += __shfl_xor(acc, 1, 64);
        acc += __shfl_xor(acc, 2, 64);
        if (qq == 0) scores[p0 + px] = acc + cb[0];
    }
}

// ---------------------------------------------------------------------------
extern "C" void kernel_launch(void* const* d_in, const int* in_sizes, int n_in,
                              void* d_out, int out_size, void* d_ws, size_t ws_size,
                              hipStream_t stream) {
    const float* corr   = (const float*)d_in[0];
    const float* det1   = (const float*)d_in[2];
    const float* det2   = (const float*)d_in[3];
    const float* c1w    = (const float*)d_in[4];
    const float* c1b    = (const float*)d_in[5];
    const float* c2w    = (const float*)d_in[6];
    const float* c2b    = (const float*)d_in[7];
    const float* c3w    = (const float*)d_in[8];
    const float* c3b    = (const float*)d_in[9];
    const float* hw     = (const float*)d_in[10];
    const float* hbias  = (const float*)d_in[11];
    const float* f6w    = (const float*)d_in[12];
    const float* f6b    = (const float*)d_in[13];
    const float* f7w    = (const float*)d_in[14];
    const float* f7b    = (const float*)d_in[15];
    const float* clsw   = (const float*)d_in[16];
    const float* clsb   = (const float*)d_in[17];
    float* out = (float*)d_out;

    char* base = (char*)d_ws;
    auto alloc = [&](size_t bytes) { char* p = base; base += (bytes + 255) & ~(size_t)255; return p; };

    const size_t ACTP_BYTES = (size_t)NB * 98 * 98 * 256 * 2;
    u16*   act1p = (u16*)  alloc(ACTP_BYTES);
    u16*   act2p = (u16*)  alloc(ACTP_BYTES);
    u16*   rel   = (u16*)  alloc((size_t)NB * PIX * 128 * 2);
    u16*   wt1f  = (u16*)  alloc((size_t)90112 * 2);
    u16*   wt2f  = (u16*)  alloc((size_t)2 * 16 * CWSTG * 2);
    u16*   wt3f  = (u16*)  alloc((size_t)16 * CWSTG * 2);
    u16*   wtHt  = (u16*)  alloc((size_t)256 * KRF * 2);
    u16*   w6c   = (u16*)  alloc(256 * 256 * 2);
    u16*   w7c   = (u16*)  alloc(256 * 256 * 2);
    float* wsum4 = (float*)alloc(256 * 4 * 4);
    u16*   rf    = (u16*)  alloc((size_t)NROI * KRF * 2);
    float* Gpart = (float*)alloc((size_t)SPLITS * NROI * 256 * 4);

    float* scores_out = out;
    float* labels_out = out + NPAIR;
    float* valid_out  = out + 2 * NPAIR;

    prep_v2<<<732, 256, 0, stream>>>(c1w, c2w, c3w, hw, f6w, f7w,
                                     wt1f, wt2f, wt3f, wtHt, w6c, w7c, wsum4,
                                     act1p, act2p);
    conv1_v4<<<dim3(72, NB), 512, 0, stream>>>(corr, wt1f, c1b, act1p);
    conv3x3_v5<3, true, 256><<<dim3(32, 2, NB), 256, 0, stream>>>(act1p, wt2f, c2b, act2p);
    conv3x3_v5<2, false, 128><<<dim3(48, 1, NB), 256, 0, stream>>>(act2p, wt3f, c3b, rel);
    roi_align_cl<<<NROI, 256, 0, stream>>>(rel, det1, rf);
    head_gemm_mfma<<<dim3(6, SPLITS), 256, 0, stream>>>(rf, wtHt, Gpart);
    pair_head<<<144, 256, 0, stream>>>(Gpart, det1, det2, wsum4, hbias,
                                       w6c, f6b, w7c, f7b, clsw, clsb,
                                       scores_out, labels_out, valid_out);
}